// Round 1
// baseline (43697.797 us; speedup 1.0000x reference)
//
#include <hip/hip_runtime.h>
#include <cstdint>

#define NBLK 128
#define BLOCK 1024
#define ROWS 32            // hidden rows per block: 128*32 = 4096
#define HDIM 4096
#define IDIM 64
#define ODIM 16
#define TSTEPS 4096
#define PAD 544            // ELL pad: mean nnz/row = 409.6, sigma = 19.2 -> 7 sigma headroom
#define LEAK 0.9f

// ---------------- init workspace (barrier words) ----------------
__global__ void init_ws(unsigned* ws) {
    if (threadIdx.x == 0) {
        __hip_atomic_store(&ws[0],  0u, __ATOMIC_RELAXED, __HIP_MEMORY_SCOPE_AGENT); // arrive counter
        __hip_atomic_store(&ws[16], 0u, __ATOMIC_RELAXED, __HIP_MEMORY_SCOPE_AGENT); // release flag (step #)
    }
}

// ---------------- persistent ESN kernel ----------------
__global__ __launch_bounds__(BLOCK) void esn_kernel(
    const float* __restrict__ X,     // [T][I]
    const float* __restrict__ Win,   // [H][I]
    const float* __restrict__ Wres,  // [H][H]
    const float* __restrict__ bvec,  // [H]
    const float* __restrict__ Wfb,   // [H][O]
    const float* __restrict__ Wout,  // [O][H]
    float* __restrict__ out,         // results [T][O] then outputs [T][H]
    float* __restrict__ part,        // [2][O][NBLK] partials
    unsigned* __restrict__ ws_u)     // [0]=cnt, [16]=flag
{
    __shared__ float          ell_val[ROWS][PAD];   // 69632 B
    __shared__ unsigned short ell_idx[ROWS][PAD];   // 34816 B
    __shared__ float          s_lds[HDIM];          // 16384 B
    __shared__ float          win_lds[ROWS][IDIM];  //  8192 B
    __shared__ float          wfb_lds[ROWS][ODIM];  //  2048 B
    __shared__ float          wout_lds[ODIM][ROWS]; //  2048 B
    __shared__ float          b_lds[ROWS];
    __shared__ int            cnt_lds[ROWS];
    __shared__ float          x_lds[IDIM];
    __shared__ float          y_lds[ODIM];
    __shared__ float          snew_lds[ROWS];

    const int tid   = threadIdx.x;
    const int blk   = blockIdx.x;
    const int rbase = blk * ROWS;

    // ---- build ELL chunk in LDS: wave w compacts rows 2w, 2w+1 ----
    {
        const int wave = tid >> 6;
        const int lane = tid & 63;
        for (int rr = wave * 2; rr < wave * 2 + 2; ++rr) {
            const float* wrow = Wres + (size_t)(rbase + rr) * HDIM;
            int base = 0;
            for (int c0 = 0; c0 < HDIM; c0 += 64) {
                float w = wrow[c0 + lane];
                unsigned long long m = __ballot(w != 0.0f);
                int before = __popcll(m & ((1ull << lane) - 1ull));
                if (w != 0.0f && (base + before) < PAD) {
                    ell_val[rr][base + before] = w;
                    ell_idx[rr][base + before] = (unsigned short)(c0 + lane);
                }
                base += __popcll(m);
            }
            if (base > PAD) base = PAD;
            if (lane == 0) cnt_lds[rr] = base;
            for (int e = base + lane; e < PAD; e += 64) {
                ell_val[rr][e] = 0.0f;
                ell_idx[rr][e] = 0;
            }
        }
    }
    // ---- small weights into LDS ----
    for (int i = tid; i < ROWS * IDIM; i += BLOCK)
        win_lds[i >> 6][i & 63] = Win[(size_t)(rbase + (i >> 6)) * IDIM + (i & 63)];
    for (int i = tid; i < ROWS * ODIM; i += BLOCK)
        wfb_lds[i >> 4][i & 15] = Wfb[(size_t)(rbase + (i >> 4)) * ODIM + (i & 15)];
    for (int i = tid; i < ODIM * ROWS; i += BLOCK)
        wout_lds[i >> 5][i & 31] = Wout[(size_t)(i >> 5) * HDIM + rbase + (i & 31)];
    if (tid < ROWS) b_lds[tid] = bvec[rbase + tid];
    __syncthreads();

    float* out_res = out;                          // [T][O]
    float* out_s   = out + (size_t)TSTEPS * ODIM;  // [T][H]
    unsigned* cnt_g  = ws_u + 0;
    unsigned* flag_g = ws_u + 16;

    for (int t = 0; t < TSTEPS; ++t) {
        // ---- phase A: load s_{t-1}, reduce y_{t-1} partials, load x_t ----
        if (tid < 128) {
            const int o = tid >> 3, j = tid & 7;
            float sum = 0.0f;
            if (t > 0) {
                float* pp = part + ((size_t)((t - 1) & 1) * ODIM + o) * NBLK + j * 16;
                #pragma unroll
                for (int k = 0; k < 16; ++k)
                    sum += __hip_atomic_load(pp + k, __ATOMIC_RELAXED, __HIP_MEMORY_SCOPE_AGENT);
            }
            sum += __shfl_down(sum, 4, 8);
            sum += __shfl_down(sum, 2, 8);
            sum += __shfl_down(sum, 1, 8);
            if (j == 0) {
                y_lds[o] = sum;
                if (blk == 0 && t > 0) out_res[(size_t)(t - 1) * ODIM + o] = sum;
            }
        } else {
            const int i0 = tid - 128;
            if (t > 0) {
                float* sp = out_s + (size_t)(t - 1) * HDIM;
                for (int i = i0; i < HDIM; i += 896)
                    s_lds[i] = __hip_atomic_load(sp + i, __ATOMIC_RELAXED, __HIP_MEMORY_SCOPE_AGENT);
            } else {
                for (int i = i0; i < HDIM; i += 896) s_lds[i] = 0.0f;
            }
            if (tid >= 960) x_lds[tid - 960] = X[(size_t)t * IDIM + (tid - 960)];
        }
        __syncthreads();

        // ---- phase B: pre = Wres@s + Win@x + Wfb@y + b ; s_new ----
        {
            const int row = tid >> 5;
            const int l   = tid & 31;
            float acc = 0.0f;
            const int rounds = (cnt_lds[row] + 31) >> 5;
            for (int k = 0; k < rounds; ++k) {
                const int e = (k << 5) + l;
                acc += ell_val[row][e] * s_lds[ell_idx[row][e]];
            }
            acc += win_lds[row][l] * x_lds[l] + win_lds[row][l + 32] * x_lds[l + 32];
            if (l < ODIM) acc += wfb_lds[row][l] * y_lds[l];
            acc += __shfl_xor(acc, 16, 32);
            acc += __shfl_xor(acc, 8, 32);
            acc += __shfl_xor(acc, 4, 32);
            acc += __shfl_xor(acc, 2, 32);
            acc += __shfl_xor(acc, 1, 32);
            if (l == 0) {
                const int r = rbase + row;
                const float pre = acc + b_lds[row];
                const float sn  = (1.0f - LEAK) * s_lds[r] + LEAK * tanhf(pre);
                snew_lds[row] = sn;
                __hip_atomic_store(out_s + (size_t)t * HDIM + r, sn,
                                   __ATOMIC_RELAXED, __HIP_MEMORY_SCOPE_AGENT);
            }
        }
        __syncthreads();

        // ---- phase C: per-block y partials ----
        if (tid < ODIM) {
            float p = 0.0f;
            #pragma unroll
            for (int r = 0; r < ROWS; ++r) p += wout_lds[tid][r] * snew_lds[r];
            __hip_atomic_store(part + ((size_t)(t & 1) * ODIM + tid) * NBLK + blk, p,
                               __ATOMIC_RELAXED, __HIP_MEMORY_SCOPE_AGENT);
        }
        __syncthreads();   // drains all vmem stores of this block (vmcnt(0) before s_barrier)

        // ---- phase D: device-wide barrier ----
        if (tid == 0) {
            unsigned old = __hip_atomic_fetch_add(cnt_g, 1u, __ATOMIC_ACQ_REL, __HIP_MEMORY_SCOPE_AGENT);
            if (old == (unsigned)(t + 1) * NBLK - 1u)
                __hip_atomic_store(flag_g, (unsigned)(t + 1), __ATOMIC_RELEASE, __HIP_MEMORY_SCOPE_AGENT);
            while (__hip_atomic_load(flag_g, __ATOMIC_ACQUIRE, __HIP_MEMORY_SCOPE_AGENT) < (unsigned)(t + 1))
                __builtin_amdgcn_s_sleep(1);
        }
        __syncthreads();
    }

    // ---- final y_{T-1} ----
    if (blk == 0 && tid < 128) {
        const int o = tid >> 3, j = tid & 7;
        float sum = 0.0f;
        float* pp = part + ((size_t)((TSTEPS - 1) & 1) * ODIM + o) * NBLK + j * 16;
        #pragma unroll
        for (int k = 0; k < 16; ++k)
            sum += __hip_atomic_load(pp + k, __ATOMIC_RELAXED, __HIP_MEMORY_SCOPE_AGENT);
        sum += __shfl_down(sum, 4, 8);
        sum += __shfl_down(sum, 2, 8);
        sum += __shfl_down(sum, 1, 8);
        if (j == 0) out_res[(size_t)(TSTEPS - 1) * ODIM + o] = sum;
    }
}

extern "C" void kernel_launch(void* const* d_in, const int* in_sizes, int n_in,
                              void* d_out, int out_size, void* d_ws, size_t ws_size,
                              hipStream_t stream) {
    (void)in_sizes; (void)n_in; (void)out_size; (void)ws_size;
    const float* X    = (const float*)d_in[0];
    const float* Win  = (const float*)d_in[1];
    const float* Wres = (const float*)d_in[2];
    const float* b    = (const float*)d_in[3];
    const float* Wfb  = (const float*)d_in[4];
    const float* Wout = (const float*)d_in[5];
    float* out = (float*)d_out;
    unsigned* ws_u = (unsigned*)d_ws;
    float* part = (float*)d_ws + 64;   // 256 B offset, after barrier words

    init_ws<<<1, 64, 0, stream>>>(ws_u);
    esn_kernel<<<NBLK, BLOCK, 0, stream>>>(X, Win, Wres, b, Wfb, Wout, out, part, ws_u);
}